// Round 8
// baseline (111.650 us; speedup 1.0000x reference)
//
#include <hip/hip_runtime.h>
#include <hip/hip_bf16.h>

// Shapes (hard-coded): B=16, Wn=64, K=256, E=128, O=64
// x:(16,64,256) lin_w:(128,128) lin_b:(128) a:(128) bias_kk:(256,256)
// fc_w:(64,256) fc_b:(64)  out:(16,64,64) fp32
//
// NOTE (R5): cooperative-kernel fusion regressed 106->233 us (grid.sync ~65us
// on MI355X across 8 non-coherent XCDs). Keep three dispatches.
// NOTE (R6/R7): k_attn is latency-bound reading k_proj's freshly written
// left/right/v. XCD swizzle (blk&7 = XCD owns b in {2x,2x+1}) helped some;
// R8 doubles occupancy (1024 blocks x 4/CU, 16 waves/CU, LDS 24.7 KB) to
// hide the residual L2/HBM latency.
#define ALPHA 0.2f
#define C1 0.6f   // (1+ALPHA)/2
#define C2 0.4f   // (1-ALPHA)/2

// ---------------- Kernel A: left/right projections + v transpose ----------
// grid = B * (K/8) = 512 blocks, 256 threads. Tile of 8 k's per block.
// XCD swizzle: x = blk&7, s = blk>>3; b = 2x + (s&1), k0 = (s>>1)*8.
__global__ __launch_bounds__(256) void k_proj(
    const float* __restrict__ x, const float* __restrict__ lin_w,
    float* __restrict__ left, float* __restrict__ right, float* __restrict__ v) {
  const int xcd = blockIdx.x & 7;
  const int s   = blockIdx.x >> 3;
  const int b   = 2 * xcd + (s & 1);
  const int k0  = (s >> 1) * 8;
  const int tid = threadIdx.x;

  __shared__ float s_x[8][68];  // [k][w]

  // load x[b, w, k0:k0+8] -> s_x[k][w] (transpose). float2 over k.
  {
    const int w  = tid >> 2;      // 0..63
    const int kq = tid & 3;       // 0..3
    float2 xv = *(const float2*)(x + b * 16384 + w * 256 + k0 + kq * 2);
    s_x[kq * 2 + 0][w] = xv.x;
    s_x[kq * 2 + 1][w] = xv.y;
  }
  __syncthreads();

  // write v[b, k, w] (coalesced float4), threads 0..127
  if (tid < 128) {
    const int k  = tid >> 4;      // 0..7
    const int wq = tid & 15;      // 0..15
    float4 vv = *(const float4*)&s_x[k][wq * 4];
    *(float4*)(v + (b * 256 + k0 + k) * 64 + wq * 4) = vv;
  }

  // compute left/right: thread = (e = tid&127, kh = tid>>7); 4 k's each.
  const int e  = tid & 127;
  const int kh = tid >> 7;  // 0..1
  float accL[4] = {0, 0, 0, 0};
  float accR[4] = {0, 0, 0, 0};
  const float4* w1 = (const float4*)(lin_w + e * 128);       // W1 row e
  const float4* w2 = w1 + 16;                                // W2 row e
#pragma unroll
  for (int wc = 0; wc < 16; ++wc) {
    float4 l = w1[wc];
    float4 r = w2[wc];
#pragma unroll
    for (int k = 0; k < 4; ++k) {
      float4 sx = *(const float4*)&s_x[kh * 4 + k][wc * 4];  // broadcast
      accL[k] += sx.x * l.x + sx.y * l.y + sx.z * l.z + sx.w * l.w;
      accR[k] += sx.x * r.x + sx.y * r.y + sx.z * r.z + sx.w * r.w;
    }
  }
#pragma unroll
  for (int k = 0; k < 4; ++k) {
    int kk = (b * 256 + k0 + kh * 4 + k) * 128 + e;
    left[kk]  = accL[k];
    right[kk] = accR[k];
  }
}

// ---------------- Kernel B: scores + softmax + attn*v + sigmoid -----------
// grid = B*(K/4) = 1024 blocks (4/CU -> 16 waves/CU), 256 threads (= j).
// XCD swizzle: x = blk&7, s = blk>>3 (0..127); b = 2x + (s&1), i0 = (s>>1)*4.
// Softmax WITHOUT max-subtraction: scores are O(+-5), exp fp32-safe
// (verified absmax ~1e-3 since R4).
__global__ __launch_bounds__(256) void k_attn(
    const float* __restrict__ left, const float* __restrict__ right,
    const float* __restrict__ lin_b, const float* __restrict__ a,
    const float* __restrict__ bias_kk, const float* __restrict__ v,
    float* __restrict__ h) {
  const int xcd  = blockIdx.x & 7;
  const int sblk = blockIdx.x >> 3;
  const int b    = 2 * xcd + (sblk & 1);
  const int i0   = (sblk >> 1) * 4;
  const int tid  = threadIdx.x;  // = j in score phase

  __shared__ float s_lb[4][132];    // left[b,i0+i,:] + lin_b
  __shared__ float s_a[128];
  __shared__ float s_ca[128];       // C2 * a
  __shared__ float s_AL[4];
  __shared__ float s_sc[4][260];    // exp(score) (unnormalized p)
  __shared__ float s_inv[4];
  __shared__ float s_v[64][68];     // v j-chunk (64 rows)  -> total ~24.7 KB

  // ---- prefetch bias_kk row elements early (hide L2 latency) ----
  float bk[4];
#pragma unroll
  for (int i = 0; i < 4; ++i) bk[i] = bias_kk[(i0 + i) * 256 + tid];

  // ---- stage left-tile (+lin_b), a, 0.4*a ----
  if (tid < 128) {
    float av = a[tid];
    s_a[tid]  = av;
    s_ca[tid] = C2 * av;
  }
  if (tid < 128) {
    const int ii = tid >> 5;      // 0..3
    const int e4 = (tid & 31) * 4;
    float4 lv = *(const float4*)(left + (b * 256 + i0 + ii) * 128 + e4);
    float4 bv = *(const float4*)(lin_b + e4);
    lv.x += bv.x; lv.y += bv.y; lv.z += bv.z; lv.w += bv.w;
    *(float4*)&s_lb[ii][e4] = lv;
  }
  __syncthreads();  // b1

  // ---- AL[i] = sum_e a_e * lb[i][e] (32-lane groups, threads 0..127) ----
  if (tid < 128) {
    const int ii = tid >> 5, sl = tid & 31;
    float p = 0.f;
#pragma unroll
    for (int m = 0; m < 4; ++m) p += s_a[sl * 4 + m] * s_lb[ii][sl * 4 + m];
#pragma unroll
    for (int off = 16; off > 0; off >>= 1) p += __shfl_xor(p, off, 64);
    if (sl == 0) s_AL[ii] = p;
  }

  // ---- scores: acc[i] = sum_e (0.4 a_e)*|lb[i][e]+r[e]|, ar = sum_e a_e r[e]
  float acc[4] = {0.f, 0.f, 0.f, 0.f};
  float ar = 0.f;
  const float4* rp = (const float4*)(right + (b * 256 + tid) * 128);
#pragma unroll
  for (int ec = 0; ec < 8; ++ec) {
    float4 r0 = rp[ec * 4 + 0], r1 = rp[ec * 4 + 1],
           r2 = rp[ec * 4 + 2], r3 = rp[ec * 4 + 3];
    float4 a0 = *(const float4*)&s_a[ec * 16 + 0];
    float4 a1 = *(const float4*)&s_a[ec * 16 + 4];
    float4 a2 = *(const float4*)&s_a[ec * 16 + 8];
    float4 a3 = *(const float4*)&s_a[ec * 16 + 12];
    ar += a0.x * r0.x + a0.y * r0.y + a0.z * r0.z + a0.w * r0.w;
    ar += a1.x * r1.x + a1.y * r1.y + a1.z * r1.z + a1.w * r1.w;
    ar += a2.x * r2.x + a2.y * r2.y + a2.z * r2.z + a2.w * r2.w;
    ar += a3.x * r3.x + a3.y * r3.y + a3.z * r3.z + a3.w * r3.w;
    float4 c0 = *(const float4*)&s_ca[ec * 16 + 0];
    float4 c1 = *(const float4*)&s_ca[ec * 16 + 4];
    float4 c2 = *(const float4*)&s_ca[ec * 16 + 8];
    float4 c3 = *(const float4*)&s_ca[ec * 16 + 12];
#pragma unroll
    for (int i = 0; i < 4; ++i) {
      float4 l0 = *(const float4*)&s_lb[i][ec * 16 + 0];
      float4 l1 = *(const float4*)&s_lb[i][ec * 16 + 4];
      float4 l2 = *(const float4*)&s_lb[i][ec * 16 + 8];
      float4 l3 = *(const float4*)&s_lb[i][ec * 16 + 12];
      float t, s = acc[i];
      t = l0.x + r0.x; s = fmaf(c0.x, fabsf(t), s);
      t = l0.y + r0.y; s = fmaf(c0.y, fabsf(t), s);
      t = l0.z + r0.z; s = fmaf(c0.z, fabsf(t), s);
      t = l0.w + r0.w; s = fmaf(c0.w, fabsf(t), s);
      t = l1.x + r1.x; s = fmaf(c1.x, fabsf(t), s);
      t = l1.y + r1.y; s = fmaf(c1.y, fabsf(t), s);
      t = l1.z + r1.z; s = fmaf(c1.z, fabsf(t), s);
      t = l1.w + r1.w; s = fmaf(c1.w, fabsf(t), s);
      t = l2.x + r2.x; s = fmaf(c2.x, fabsf(t), s);
      t = l2.y + r2.y; s = fmaf(c2.y, fabsf(t), s);
      t = l2.z + r2.z; s = fmaf(c2.z, fabsf(t), s);
      t = l2.w + r2.w; s = fmaf(c2.w, fabsf(t), s);
      t = l3.x + r3.x; s = fmaf(c3.x, fabsf(t), s);
      t = l3.y + r3.y; s = fmaf(c3.y, fabsf(t), s);
      t = l3.z + r3.z; s = fmaf(c3.z, fabsf(t), s);
      t = l3.w + r3.w; s = fmaf(c3.w, fabsf(t), s);
      acc[i] = s;
    }
  }
  __syncthreads();  // b2 (s_AL visible)

  // ---- finalize + exp (no max-subtraction), write p into s_sc ----
#pragma unroll
  for (int i = 0; i < 4; ++i) {
    float sc = fmaf(C1, s_AL[i] + ar, acc[i]) + bk[i];
    s_sc[i][tid] = __expf(sc);
  }
  __syncthreads();  // b3

  // ---- row sum -> 1/sum (1 row per wave) ----
  {
    const int wv = tid >> 6, lane = tid & 63;
    float s = s_sc[wv][lane] + s_sc[wv][lane + 64] +
              s_sc[wv][lane + 128] + s_sc[wv][lane + 192];
#pragma unroll
    for (int off = 32; off > 0; off >>= 1) s += __shfl_xor(s, off, 64);
    if (lane == 0) s_inv[wv] = 1.f / s;
  }

  // ---- h[i,w] = sigmoid( (sum_j p_j * v[j,w]) * inv[i] ) ----
  const int iq = tid >> 6;          // 0..3
  const int w  = tid & 63;          // 0..63
  float h0 = 0.f;
#pragma unroll
  for (int c = 0; c < 4; ++c) {
    __syncthreads();  // c=0: s_inv/s_sc ready; later: protect s_v reuse
#pragma unroll
    for (int t = 0; t < 4; ++t) {
      int idx = tid + t * 256;          // 0..1023
      int row = idx >> 4, col = (idx & 15) * 4;
      *(float4*)&s_v[row][col] =
          *(const float4*)(v + (b * 256 + c * 64 + row) * 64 + col);
    }
    __syncthreads();
#pragma unroll 4
    for (int jj = 0; jj < 64; jj += 4) {
      float4 at = *(const float4*)&s_sc[iq][c * 64 + jj];
      h0 += at.x * s_v[jj + 0][w] + at.y * s_v[jj + 1][w] +
            at.z * s_v[jj + 2][w] + at.w * s_v[jj + 3][w];
    }
  }
  h[(b * 256 + i0 + iq) * 64 + w] = 1.f / (1.f + __expf(-h0 * s_inv[iq]));
}

// ---------------- Kernel C: out[b,w,o] = sum_k h[b,k,w]*fc_w[o,k] + fc_b --
// grid = 256 blocks, 256 threads. XCD swizzle: x = blk&7, s = blk>>3 (0..31);
// b = 2x + (s&1), wg = s>>1 -> h[b] consumed on the XCD that produced it.
__global__ __launch_bounds__(256) void k_out(
    const float* __restrict__ h, const float* __restrict__ fc_w,
    const float* __restrict__ fc_b, float* __restrict__ out) {
  const int xcd = blockIdx.x & 7;
  const int s   = blockIdx.x >> 3;
  const int b   = 2 * xcd + (s & 1);
  const int wg  = s >> 1;        // group of 4 w's
  const int wl  = threadIdx.x >> 6;
  const int o   = threadIdx.x & 63;
  const int w   = wg * 4 + wl;

  __shared__ float s_h[256 * 4];  // [k][wl]
  for (int idx = threadIdx.x; idx < 1024; idx += 256) {
    int k = idx >> 2, wl2 = idx & 3;
    s_h[idx] = h[(b * 256 + k) * 64 + wg * 4 + wl2];
  }
  __syncthreads();

  float acc = 0.f;
  const float4* fw = (const float4*)(fc_w + o * 256);
#pragma unroll
  for (int k4 = 0; k4 < 64; ++k4) {
    float4 f = fw[k4];
    int k = k4 * 4;
    acc += s_h[(k + 0) * 4 + wl] * f.x + s_h[(k + 1) * 4 + wl] * f.y +
           s_h[(k + 2) * 4 + wl] * f.z + s_h[(k + 3) * 4 + wl] * f.w;
  }
  out[b * 64 * 64 + w * 64 + o] = acc + fc_b[o];
}

extern "C" void kernel_launch(void* const* d_in, const int* in_sizes, int n_in,
                              void* d_out, int out_size, void* d_ws, size_t ws_size,
                              hipStream_t stream) {
  const float* x       = (const float*)d_in[0];
  const float* lin_w   = (const float*)d_in[1];
  const float* lin_b   = (const float*)d_in[2];
  const float* a       = (const float*)d_in[3];
  const float* bias_kk = (const float*)d_in[4];
  const float* fc_w    = (const float*)d_in[5];
  const float* fc_b    = (const float*)d_in[6];
  float* out = (float*)d_out;

  float* ws    = (float*)d_ws;
  float* left  = ws;                // 16*256*128 = 524288
  float* right = ws + 524288;       // 524288
  float* v     = ws + 1048576;      // 16*256*64 = 262144
  float* h     = ws + 1310720;      // 262144

  k_proj<<<512, 256, 0, stream>>>(x, lin_w, left, right, v);
  k_attn<<<1024, 256, 0, stream>>>(left, right, lin_b, a, bias_kk, v, h);
  k_out<<<256, 256, 0, stream>>>(h, fc_w, fc_b, out);
}

// Round 9
// 104.107 us; speedup vs baseline: 1.0725x; 1.0725x over previous
//
#include <hip/hip_runtime.h>
#include <hip/hip_bf16.h>

// Shapes (hard-coded): B=16, Wn=64, K=256, E=128, O=64
// x:(16,64,256) lin_w:(128,128) lin_b:(128) a:(128) bias_kk:(256,256)
// fc_w:(64,256) fc_b:(64)  out:(16,64,64) fp32
//
// Tuning history (MI355X):
//  R5: cooperative-kernel fusion regressed 106->233 us (grid.sync ~65 us
//      across 8 non-coherent XCDs). Keep three dispatches.
//  R6->R7: XCD swizzle (blk&7 = XCD; XCD x owns b in {2x,2x+1} for producer
//      AND consumers) cut k_attn's cross-XCD HBM refetch; best = 104.3 us.
//  R8: i-tile 8->4 + 1024 blocks REGRESSED to 111.7 us (per-block right/v
//      re-read doubled; latency-bound => more traffic = more stalls).
//      Tile 8 @ 512 blocks (2/CU) is the optimum of this family.
//  dur_us is dominated by ~85-90 us of harness reset (268 MB 0xAA poison
//  fill at 6.3 TB/s visible as fillBufferAligned in every profile).
#define ALPHA 0.2f
#define C1 0.6f   // (1+ALPHA)/2
#define C2 0.4f   // (1-ALPHA)/2

// ---------------- Kernel A: left/right projections + v transpose ----------
// grid = B * (K/8) = 512 blocks (2/CU), 256 threads. Tile of 8 k's per block.
// XCD swizzle: x = blk&7, s = blk>>3; b = 2x + (s&1), k0 = (s>>1)*8.
__global__ __launch_bounds__(256) void k_proj(
    const float* __restrict__ x, const float* __restrict__ lin_w,
    float* __restrict__ left, float* __restrict__ right, float* __restrict__ v) {
  const int xcd = blockIdx.x & 7;
  const int s   = blockIdx.x >> 3;
  const int b   = 2 * xcd + (s & 1);
  const int k0  = (s >> 1) * 8;
  const int tid = threadIdx.x;

  __shared__ float s_x[8][68];  // [k][w]

  // load x[b, w, k0:k0+8] -> s_x[k][w] (transpose). float2 over k.
  {
    const int w  = tid >> 2;      // 0..63
    const int kq = tid & 3;       // 0..3
    float2 xv = *(const float2*)(x + b * 16384 + w * 256 + k0 + kq * 2);
    s_x[kq * 2 + 0][w] = xv.x;
    s_x[kq * 2 + 1][w] = xv.y;
  }
  __syncthreads();

  // write v[b, k, w] (coalesced float4), threads 0..127
  if (tid < 128) {
    const int k  = tid >> 4;      // 0..7
    const int wq = tid & 15;      // 0..15
    float4 vv = *(const float4*)&s_x[k][wq * 4];
    *(float4*)(v + (b * 256 + k0 + k) * 64 + wq * 4) = vv;
  }

  // compute left/right: thread = (e = tid&127, kh = tid>>7); 4 k's each.
  const int e  = tid & 127;
  const int kh = tid >> 7;  // 0..1
  float accL[4] = {0, 0, 0, 0};
  float accR[4] = {0, 0, 0, 0};
  const float4* w1 = (const float4*)(lin_w + e * 128);       // W1 row e
  const float4* w2 = w1 + 16;                                // W2 row e
#pragma unroll
  for (int wc = 0; wc < 16; ++wc) {
    float4 l = w1[wc];
    float4 r = w2[wc];
#pragma unroll
    for (int k = 0; k < 4; ++k) {
      float4 sx = *(const float4*)&s_x[kh * 4 + k][wc * 4];  // broadcast
      accL[k] += sx.x * l.x + sx.y * l.y + sx.z * l.z + sx.w * l.w;
      accR[k] += sx.x * r.x + sx.y * r.y + sx.z * r.z + sx.w * r.w;
    }
  }
#pragma unroll
  for (int k = 0; k < 4; ++k) {
    int kk = (b * 256 + k0 + kh * 4 + k) * 128 + e;
    left[kk]  = accL[k];
    right[kk] = accR[k];
  }
}

// ---------------- Kernel B: scores + softmax + attn*v + sigmoid -----------
// grid = 512 blocks, 256 threads (= j). XCD swizzle matches k_proj:
// x = blk&7, s = blk>>3; b = 2x + (s&1), i0 = (s>>1)*8 -> right/v/left for b
// are in this XCD's L2 (written here by k_proj).
// Softmax WITHOUT max-subtraction: scores are O(+-5), exp fp32-safe
// (verified absmax ~1e-3 since R4).
__global__ __launch_bounds__(256) void k_attn(
    const float* __restrict__ left, const float* __restrict__ right,
    const float* __restrict__ lin_b, const float* __restrict__ a,
    const float* __restrict__ bias_kk, const float* __restrict__ v,
    float* __restrict__ h) {
  const int xcd = blockIdx.x & 7;
  const int sblk = blockIdx.x >> 3;
  const int b   = 2 * xcd + (sblk & 1);
  const int i0  = (sblk >> 1) * 8;
  const int tid = threadIdx.x;  // = j in score phase

  __shared__ float s_lb[8][132];    // left[b,i0+i,:] + lin_b
  __shared__ float s_a[128];
  __shared__ float s_ca[128];       // C2 * a
  __shared__ float s_AL[8];
  __shared__ float s_sc[8][260];    // exp(score) (unnormalized p)
  __shared__ float s_inv[8];
  __shared__ float s_v[128][68];    // v j-chunk (128 rows)

  // ---- prefetch bias_kk row elements early (hide L2 latency) ----
  float bk[8];
#pragma unroll
  for (int i = 0; i < 8; ++i) bk[i] = bias_kk[(i0 + i) * 256 + tid];

  // ---- stage left-tile (+lin_b), a, 0.4*a ----
  if (tid < 128) {
    float av = a[tid];
    s_a[tid]  = av;
    s_ca[tid] = C2 * av;
  }
  {
    const int ii = tid >> 5;      // 0..7
    const int e4 = (tid & 31) * 4;
    float4 lv = *(const float4*)(left + (b * 256 + i0 + ii) * 128 + e4);
    float4 bv = *(const float4*)(lin_b + e4);
    lv.x += bv.x; lv.y += bv.y; lv.z += bv.z; lv.w += bv.w;
    *(float4*)&s_lb[ii][e4] = lv;
  }
  __syncthreads();  // b1

  // ---- AL[i] = sum_e a_e * lb[i][e] (32-lane groups) ----
  {
    const int ii = tid >> 5, sl = tid & 31;
    float p = 0.f;
#pragma unroll
    for (int m = 0; m < 4; ++m) p += s_a[sl * 4 + m] * s_lb[ii][sl * 4 + m];
#pragma unroll
    for (int off = 16; off > 0; off >>= 1) p += __shfl_xor(p, off, 64);
    if (sl == 0) s_AL[ii] = p;
  }

  // ---- scores: acc[i] = sum_e (0.4 a_e)*|lb[i][e]+r[e]|, ar = sum_e a_e r[e]
  float acc[8];
#pragma unroll
  for (int i = 0; i < 8; ++i) acc[i] = 0.f;
  float ar = 0.f;
  const float4* rp = (const float4*)(right + (b * 256 + tid) * 128);
#pragma unroll
  for (int ec = 0; ec < 8; ++ec) {
    float4 r0 = rp[ec * 4 + 0], r1 = rp[ec * 4 + 1],
           r2 = rp[ec * 4 + 2], r3 = rp[ec * 4 + 3];
    float4 a0 = *(const float4*)&s_a[ec * 16 + 0];
    float4 a1 = *(const float4*)&s_a[ec * 16 + 4];
    float4 a2 = *(const float4*)&s_a[ec * 16 + 8];
    float4 a3 = *(const float4*)&s_a[ec * 16 + 12];
    ar += a0.x * r0.x + a0.y * r0.y + a0.z * r0.z + a0.w * r0.w;
    ar += a1.x * r1.x + a1.y * r1.y + a1.z * r1.z + a1.w * r1.w;
    ar += a2.x * r2.x + a2.y * r2.y + a2.z * r2.z + a2.w * r2.w;
    ar += a3.x * r3.x + a3.y * r3.y + a3.z * r3.z + a3.w * r3.w;
    float4 c0 = *(const float4*)&s_ca[ec * 16 + 0];
    float4 c1 = *(const float4*)&s_ca[ec * 16 + 4];
    float4 c2 = *(const float4*)&s_ca[ec * 16 + 8];
    float4 c3 = *(const float4*)&s_ca[ec * 16 + 12];
#pragma unroll
    for (int i = 0; i < 8; ++i) {
      float4 l0 = *(const float4*)&s_lb[i][ec * 16 + 0];
      float4 l1 = *(const float4*)&s_lb[i][ec * 16 + 4];
      float4 l2 = *(const float4*)&s_lb[i][ec * 16 + 8];
      float4 l3 = *(const float4*)&s_lb[i][ec * 16 + 12];
      float t, s = acc[i];
      t = l0.x + r0.x; s = fmaf(c0.x, fabsf(t), s);
      t = l0.y + r0.y; s = fmaf(c0.y, fabsf(t), s);
      t = l0.z + r0.z; s = fmaf(c0.z, fabsf(t), s);
      t = l0.w + r0.w; s = fmaf(c0.w, fabsf(t), s);
      t = l1.x + r1.x; s = fmaf(c1.x, fabsf(t), s);
      t = l1.y + r1.y; s = fmaf(c1.y, fabsf(t), s);
      t = l1.z + r1.z; s = fmaf(c1.z, fabsf(t), s);
      t = l1.w + r1.w; s = fmaf(c1.w, fabsf(t), s);
      t = l2.x + r2.x; s = fmaf(c2.x, fabsf(t), s);
      t = l2.y + r2.y; s = fmaf(c2.y, fabsf(t), s);
      t = l2.z + r2.z; s = fmaf(c2.z, fabsf(t), s);
      t = l2.w + r2.w; s = fmaf(c2.w, fabsf(t), s);
      t = l3.x + r3.x; s = fmaf(c3.x, fabsf(t), s);
      t = l3.y + r3.y; s = fmaf(c3.y, fabsf(t), s);
      t = l3.z + r3.z; s = fmaf(c3.z, fabsf(t), s);
      t = l3.w + r3.w; s = fmaf(c3.w, fabsf(t), s);
      acc[i] = s;
    }
  }
  __syncthreads();  // b2 (s_AL visible)

  // ---- finalize + exp (no max-subtraction), write p into s_sc ----
#pragma unroll
  for (int i = 0; i < 8; ++i) {
    float sc = fmaf(C1, s_AL[i] + ar, acc[i]) + bk[i];
    s_sc[i][tid] = __expf(sc);
  }
  __syncthreads();  // b3

  // ---- row sum -> 1/sum (2 rows per wave) ----
  {
    const int wv = tid >> 6, lane = tid & 63;
#pragma unroll
    for (int rr = 0; rr < 2; ++rr) {
      int i = wv * 2 + rr;
      float s = s_sc[i][lane] + s_sc[i][lane + 64] +
                s_sc[i][lane + 128] + s_sc[i][lane + 192];
#pragma unroll
      for (int off = 32; off > 0; off >>= 1) s += __shfl_xor(s, off, 64);
      if (lane == 0) s_inv[i] = 1.f / s;
    }
  }

  // ---- h[i,w] = sigmoid( (sum_j p_j * v[j,w]) * inv[i] ) ----
  const int iq = tid >> 5;          // 0..7
  const int w  = (tid & 31) * 2;    // 0,2,..,62
  float h0 = 0.f, h1 = 0.f;
#pragma unroll
  for (int c = 0; c < 2; ++c) {
    __syncthreads();  // c=0: s_inv/s_sc ready; c=1: protect s_v reuse
#pragma unroll
    for (int t = 0; t < 8; ++t) {
      int idx = tid + t * 256;          // 0..2047
      int row = idx >> 4, col = (idx & 15) * 4;
      *(float4*)&s_v[row][col] =
          *(const float4*)(v + (b * 256 + c * 128 + row) * 64 + col);
    }
    __syncthreads();
#pragma unroll 4
    for (int jj = 0; jj < 128; jj += 4) {
      float4 at = *(const float4*)&s_sc[iq][c * 128 + jj];
      float2 v0 = *(const float2*)&s_v[jj + 0][w];
      float2 v1 = *(const float2*)&s_v[jj + 1][w];
      float2 v2 = *(const float2*)&s_v[jj + 2][w];
      float2 v3 = *(const float2*)&s_v[jj + 3][w];
      h0 += at.x * v0.x + at.y * v1.x + at.z * v2.x + at.w * v3.x;
      h1 += at.x * v0.y + at.y * v1.y + at.z * v2.y + at.w * v3.y;
    }
  }
  float inv = s_inv[iq];
  float2 hv;
  hv.x = 1.f / (1.f + __expf(-h0 * inv));
  hv.y = 1.f / (1.f + __expf(-h1 * inv));
  *(float2*)(h + (b * 256 + i0 + iq) * 64 + w) = hv;
}

// ---------------- Kernel C: out[b,w,o] = sum_k h[b,k,w]*fc_w[o,k] + fc_b --
// grid = 256 blocks, 256 threads. XCD swizzle: x = blk&7, s = blk>>3 (0..31);
// b = 2x + (s&1), wg = s>>1 -> h[b] consumed on the XCD that produced it.
__global__ __launch_bounds__(256) void k_out(
    const float* __restrict__ h, const float* __restrict__ fc_w,
    const float* __restrict__ fc_b, float* __restrict__ out) {
  const int xcd = blockIdx.x & 7;
  const int s   = blockIdx.x >> 3;
  const int b   = 2 * xcd + (s & 1);
  const int wg  = s >> 1;        // group of 4 w's
  const int wl  = threadIdx.x >> 6;
  const int o   = threadIdx.x & 63;
  const int w   = wg * 4 + wl;

  __shared__ float s_h[256 * 4];  // [k][wl]
  for (int idx = threadIdx.x; idx < 1024; idx += 256) {
    int k = idx >> 2, wl2 = idx & 3;
    s_h[idx] = h[(b * 256 + k) * 64 + wg * 4 + wl2];
  }
  __syncthreads();

  float acc = 0.f;
  const float4* fw = (const float4*)(fc_w + o * 256);
#pragma unroll
  for (int k4 = 0; k4 < 64; ++k4) {
    float4 f = fw[k4];
    int k = k4 * 4;
    acc += s_h[(k + 0) * 4 + wl] * f.x + s_h[(k + 1) * 4 + wl] * f.y +
           s_h[(k + 2) * 4 + wl] * f.z + s_h[(k + 3) * 4 + wl] * f.w;
  }
  out[b * 64 * 64 + w * 64 + o] = acc + fc_b[o];
}

extern "C" void kernel_launch(void* const* d_in, const int* in_sizes, int n_in,
                              void* d_out, int out_size, void* d_ws, size_t ws_size,
                              hipStream_t stream) {
  const float* x       = (const float*)d_in[0];
  const float* lin_w   = (const float*)d_in[1];
  const float* lin_b   = (const float*)d_in[2];
  const float* a       = (const float*)d_in[3];
  const float* bias_kk = (const float*)d_in[4];
  const float* fc_w    = (const float*)d_in[5];
  const float* fc_b    = (const float*)d_in[6];
  float* out = (float*)d_out;

  float* ws    = (float*)d_ws;
  float* left  = ws;                // 16*256*128 = 524288
  float* right = ws + 524288;       // 524288
  float* v     = ws + 1048576;      // 16*256*64 = 262144
  float* h     = ws + 1310720;      // 262144

  k_proj<<<512, 256, 0, stream>>>(x, lin_w, left, right, v);
  k_attn<<<512, 256, 0, stream>>>(left, right, lin_b, a, bias_kk, v, h);
  k_out<<<256, 256, 0, stream>>>(h, fc_w, fc_b, out);
}